// Round 1
// baseline (499.009 us; speedup 1.0000x reference)
//
#include <hip/hip_runtime.h>
#include <cstddef>

typedef __bf16 bf16_t;
typedef __bf16 bf16x8 __attribute__((ext_vector_type(8)));
typedef __bf16 bf16x4 __attribute__((ext_vector_type(4)));
typedef float  f32x4  __attribute__((ext_vector_type(4)));

// Problem constants: B=2, T=2048, D=1024, H=16, K=V=64, W=256
// ---------------------------------------------------------------------------
// RMSNorm + bf16 cast: one block per token row (4096 rows), 256 thr x 4 elems
__global__ __launch_bounds__(256) void rmsnorm_kernel(const float* __restrict__ x,
                                                      const float* __restrict__ w,
                                                      bf16_t* __restrict__ xn) {
  int t = blockIdx.x;
  int tid = threadIdx.x;
  const f32x4* row = (const f32x4*)(x + (size_t)t * 1024);
  f32x4 v = row[tid];
  float ss = v[0]*v[0] + v[1]*v[1] + v[2]*v[2] + v[3]*v[3];
  #pragma unroll
  for (int off = 32; off >= 1; off >>= 1) ss += __shfl_xor(ss, off);
  __shared__ float red[4];
  int wave = tid >> 6;
  if ((tid & 63) == 0) red[wave] = ss;
  __syncthreads();
  float tot = red[0] + red[1] + red[2] + red[3];
  float rinv = rsqrtf(tot * (1.0f / 1024.0f) + 1e-6f);
  f32x4 wv = ((const f32x4*)w)[tid];
  bf16x4 o;
  #pragma unroll
  for (int i = 0; i < 4; ++i) o[i] = (bf16_t)(v[i] * rinv * wv[i]);
  *(bf16x4*)(xn + (size_t)t * 1024 + tid * 4) = o;
}

// ---------------------------------------------------------------------------
// fp32 -> bf16 weight conversion, 6 matrices of 1024x1024
struct CvtArgs { const float* s[6]; bf16_t* d[6]; };
__global__ __launch_bounds__(256) void convert6(CvtArgs a) {
  const f32x4* src = (const f32x4*)a.s[blockIdx.y];
  bf16_t* dst = a.d[blockIdx.y];
  int i = blockIdx.x * 256 + threadIdx.x;    // 262144 f32x4 per matrix
  f32x4 v = src[i];
  bf16x4 o;
  #pragma unroll
  for (int j = 0; j < 4; ++j) o[j] = (bf16_t)v[j];
  *(bf16x4*)(dst + (size_t)i * 4) = o;
}

// ---------------------------------------------------------------------------
// bf16 MFMA GEMM, C = A (Mx1024) * W^T (1024x1024), W row-major (N x Kd).
// 128x128 block tile, 4 waves each 64x64 (4x4 grid of 16x16x32 MFMA), BK=32.
// LDS rows padded 32->40 bf16 (80B row stride: 16B-aligned, 2-way banks = free).
struct GemmSeg { const bf16_t* a; const bf16_t* w; void* c; };
struct GemmCfg { GemmSeg seg[4]; int bf16out; };
#define LDSK 40
__global__ __launch_bounds__(256, 2) void gemm_bt(GemmCfg cfg) {
  __shared__ bf16_t As[128 * LDSK];
  __shared__ bf16_t Bs[128 * LDSK];
  int seg = blockIdx.x >> 3;
  const bf16_t* __restrict__ A = cfg.seg[seg].a;
  const bf16_t* __restrict__ W = cfg.seg[seg].w;
  int m0 = blockIdx.y * 128;
  int n0 = (blockIdx.x & 7) * 128;
  int tid = threadIdx.x;
  int lane = tid & 63, wave = tid >> 6;
  int wm = (wave >> 1) * 64, wn = (wave & 1) * 64;
  int l16 = lane & 15, quad = lane >> 4;
  f32x4 acc[4][4] = {};
  for (int k0 = 0; k0 < 1024; k0 += 32) {
    __syncthreads();
    #pragma unroll
    for (int c = 0; c < 2; ++c) {
      int ci = tid + c * 256;          // 0..511 16B-chunks
      int r = ci >> 2;                 // tile row 0..127
      int ko = (ci & 3) * 8;           // k offset 0/8/16/24
      *(uint4*)&As[r * LDSK + ko] = *(const uint4*)&A[(size_t)(m0 + r) * 1024 + k0 + ko];
      *(uint4*)&Bs[r * LDSK + ko] = *(const uint4*)&W[(size_t)(n0 + r) * 1024 + k0 + ko];
    }
    __syncthreads();
    bf16x8 af[4], bfr[4];
    #pragma unroll
    for (int i = 0; i < 4; ++i) {
      af[i]  = *(const bf16x8*)&As[(wm + i * 16 + l16) * LDSK + quad * 8];
      bfr[i] = *(const bf16x8*)&Bs[(wn + i * 16 + l16) * LDSK + quad * 8];
    }
    #pragma unroll
    for (int i = 0; i < 4; ++i)
      #pragma unroll
      for (int j = 0; j < 4; ++j)
        acc[i][j] = __builtin_amdgcn_mfma_f32_16x16x32_bf16(af[i], bfr[j], acc[i][j], 0, 0, 0);
  }
  // C/D layout (verified m89/m91): col = lane&15, row = quad*4 + reg
  if (cfg.bf16out) {
    bf16_t* C = (bf16_t*)cfg.seg[seg].c;
    #pragma unroll
    for (int i = 0; i < 4; ++i)
      #pragma unroll
      for (int j = 0; j < 4; ++j) {
        int row = m0 + wm + i * 16 + quad * 4;
        int col = n0 + wn + j * 16 + l16;
        #pragma unroll
        for (int r = 0; r < 4; ++r)
          C[(size_t)(row + r) * 1024 + col] = (bf16_t)acc[i][j][r];
      }
  } else {
    float* C = (float*)cfg.seg[seg].c;
    #pragma unroll
    for (int i = 0; i < 4; ++i)
      #pragma unroll
      for (int j = 0; j < 4; ++j) {
        int row = m0 + wm + i * 16 + quad * 4;
        int col = n0 + wn + j * 16 + l16;
        #pragma unroll
        for (int r = 0; r < 4; ++r)
          C[(size_t)(row + r) * 1024 + col] = acc[i][j][r];
      }
  }
}

// ---------------------------------------------------------------------------
// RoPE on q and k (bf16 in/out). One thread per (b,t,h,d<32) pair.
__global__ __launch_bounds__(256) void rope_kernel(bf16_t* __restrict__ q,
                                                   bf16_t* __restrict__ k) {
  int idx = blockIdx.x * 256 + threadIdx.x;   // < 2*2048*16*32 = 2097152
  int d = idx & 31;
  int h = (idx >> 5) & 15;
  int t = (idx >> 9) & 2047;
  int b = idx >> 20;
  float inv = expf((float)d * (-2.0f / 64.0f) * 9.210340371976184f); // 10000^(-2d/64)
  float f = (float)t * inv;
  float sn, cs;
  sincosf(f, &sn, &cs);
  size_t base = (((size_t)(b * 2048 + t) * 16) + h) * 64;
  float q1 = (float)q[base + d], q2 = (float)q[base + d + 32];
  q[base + d]      = (bf16_t)(q1 * cs - q2 * sn);
  q[base + d + 32] = (bf16_t)(q2 * cs + q1 * sn);
  float k1 = (float)k[base + d], k2 = (float)k[base + d + 32];
  k[base + d]      = (bf16_t)(k1 * cs - k2 * sn);
  k[base + d + 32] = (bf16_t)(k2 * cs + k1 * sn);
}

// ---------------------------------------------------------------------------
// Sliding-window attention: one block = (b, h, 128 queries), 128 threads,
// thread owns one query row (q + acc in regs). Keys staged in 64-key LDS
// chunks (fp32); online softmax. Window: s in [t-256, t].
__global__ __launch_bounds__(128, 2) void attn_kernel(const bf16_t* __restrict__ qb,
                                                      const bf16_t* __restrict__ kb,
                                                      const bf16_t* __restrict__ vb,
                                                      bf16_t* __restrict__ ob) {
  __shared__ float Ks[64][64];
  __shared__ float Vs[64][64];
  int blk = blockIdx.x;            // 512 = 2*16*16
  int tq = blk & 15;
  int h = (blk >> 4) & 15;
  int b = blk >> 8;
  int t0 = tq * 128;
  int tid = threadIdx.x;
  int t = t0 + tid;
  float qreg[64];
  const bf16_t* qrow = qb + (((size_t)(b * 2048 + t) * 16) + h) * 64;
  #pragma unroll
  for (int i = 0; i < 8; ++i) {
    bf16x8 qv = *(const bf16x8*)(qrow + i * 8);
    #pragma unroll
    for (int j = 0; j < 8; ++j) qreg[i * 8 + j] = (float)qv[j];
  }
  float acc[64];
  #pragma unroll
  for (int d = 0; d < 64; ++d) acc[d] = 0.f;
  float mrun = -1e30f, lrun = 0.f;
  for (int c = 0; c < 6; ++c) {                 // keys [t0-256, t0+127] in 6x64
    int s0 = t0 - 256 + c * 64;
    __syncthreads();
    #pragma unroll
    for (int it = 0; it < 4; ++it) {
      int idx = tid + it * 128;                 // 0..511
      int sl = idx >> 3;
      int dp = (idx & 7) * 8;
      int s = s0 + sl;
      if (s >= 0 && s < 2048) {
        size_t gb = (((size_t)(b * 2048 + s) * 16) + h) * 64 + dp;
        bf16x8 kv = *(const bf16x8*)(kb + gb);
        bf16x8 vv = *(const bf16x8*)(vb + gb);
        f32x4 k0v = {(float)kv[0], (float)kv[1], (float)kv[2], (float)kv[3]};
        f32x4 k1v = {(float)kv[4], (float)kv[5], (float)kv[6], (float)kv[7]};
        f32x4 v0v = {(float)vv[0], (float)vv[1], (float)vv[2], (float)vv[3]};
        f32x4 v1v = {(float)vv[4], (float)vv[5], (float)vv[6], (float)vv[7]};
        *(f32x4*)&Ks[sl][dp] = k0v; *(f32x4*)&Ks[sl][dp + 4] = k1v;
        *(f32x4*)&Vs[sl][dp] = v0v; *(f32x4*)&Vs[sl][dp + 4] = v1v;
      } else {
        f32x4 z = {0.f, 0.f, 0.f, 0.f};
        *(f32x4*)&Ks[sl][dp] = z; *(f32x4*)&Ks[sl][dp + 4] = z;
        *(f32x4*)&Vs[sl][dp] = z; *(f32x4*)&Vs[sl][dp + 4] = z;
      }
    }
    __syncthreads();
    #pragma unroll 2
    for (int j = 0; j < 64; ++j) {
      int s = s0 + j;
      const f32x4* kr = (const f32x4*)&Ks[j][0];
      float p0 = 0.f, p1 = 0.f, p2 = 0.f, p3 = 0.f;
      #pragma unroll
      for (int i = 0; i < 16; ++i) {
        f32x4 kv = kr[i];
        p0 += qreg[i * 4 + 0] * kv[0];
        p1 += qreg[i * 4 + 1] * kv[1];
        p2 += qreg[i * 4 + 2] * kv[2];
        p3 += qreg[i * 4 + 3] * kv[3];
      }
      float score = ((p0 + p1) + (p2 + p3)) * 0.125f;
      bool ok = (s >= 0) && (s <= t) && (s >= t - 256);
      if (ok) {
        float p;
        if (score > mrun) {
          float alpha = __expf(mrun - score);
          lrun *= alpha;
          #pragma unroll
          for (int d = 0; d < 64; ++d) acc[d] *= alpha;
          mrun = score;
          p = 1.f;
        } else {
          p = __expf(score - mrun);
        }
        lrun += p;
        const f32x4* vr = (const f32x4*)&Vs[j][0];
        #pragma unroll
        for (int i = 0; i < 16; ++i) {
          f32x4 vv = vr[i];
          acc[i * 4 + 0] += p * vv[0];
          acc[i * 4 + 1] += p * vv[1];
          acc[i * 4 + 2] += p * vv[2];
          acc[i * 4 + 3] += p * vv[3];
        }
      }
    }
  }
  float rl = 1.0f / lrun;
  bf16_t* orow = ob + (((size_t)(b * 2048 + t) * 16) + h) * 64;
  #pragma unroll
  for (int i = 0; i < 8; ++i) {
    bf16x8 ov;
    #pragma unroll
    for (int j = 0; j < 8; ++j) ov[j] = (bf16_t)(acc[i * 8 + j] * rl);
    *(bf16x8*)(orow + i * 8) = ov;
  }
}

// ---------------------------------------------------------------------------
// Gate: gm[t] = mean_h sigmoid(xn[t] . w_gate[h] + b_gate[h]); one wave/token
__global__ __launch_bounds__(256, 4) void gate_kernel(const bf16_t* __restrict__ xn,
                                                      const float* __restrict__ wg,
                                                      const float* __restrict__ bg,
                                                      float* __restrict__ gm) {
  int wave = threadIdx.x >> 6, lane = threadIdx.x & 63;
  int t = blockIdx.x * 4 + wave;           // 4096 tokens
  float acc[16];
  #pragma unroll
  for (int h = 0; h < 16; ++h) acc[h] = 0.f;
  const bf16_t* xr = xn + (size_t)t * 1024;
  for (int i = 0; i < 16; ++i) {
    float xv = (float)xr[i * 64 + lane];
    #pragma unroll
    for (int h = 0; h < 16; ++h) acc[h] += xv * wg[h * 1024 + i * 64 + lane];
  }
  #pragma unroll
  for (int h = 0; h < 16; ++h) {
    float s = acc[h];
    #pragma unroll
    for (int off = 32; off >= 1; off >>= 1) s += __shfl_xor(s, off);
    acc[h] = s;
  }
  if (lane == 0) {
    float g = 0.f;
    #pragma unroll
    for (int h = 0; h < 16; ++h) g += 1.0f / (1.0f + __expf(-(acc[h] + bg[h])));
    gm[t] = g * (1.0f / 16.0f);
  }
}

// ---------------------------------------------------------------------------
// Retrieval: q_g override by key_bank gather, then retrieved = q_g @ gdn[b,h]
__global__ __launch_bounds__(256, 2) void retrieval_kernel(const bf16_t* __restrict__ qgb,
                                                           const int* __restrict__ ids,
                                                           const float* __restrict__ bank,
                                                           const float* __restrict__ gdn,
                                                           bf16_t* __restrict__ rb) {
  __shared__ float G[64 * 64];     // gdn_state[b][h], (k,v) row-major
  int blk = blockIdx.x;            // 256 = 2*16*8
  int tc = blk & 7;
  int h = (blk >> 3) & 15;
  int b = blk >> 7;
  int tid = threadIdx.x;
  const f32x4* gsrc = (const f32x4*)(gdn + (size_t)(b * 16 + h) * 4096);
  #pragma unroll
  for (int it = 0; it < 4; ++it)
    ((f32x4*)G)[tid + it * 256] = gsrc[tid + it * 256];
  __syncthreads();
  int t = tc * 256 + tid;
  int id = ids[b * 2048 + t] - 50250;
  bool valid = (id >= 0) && (id < 64);
  const bf16_t* qrow = qgb + (((size_t)(b * 2048 + t) * 16) + h) * 64;
  const float* krow = bank + (size_t)(h * 64 + (valid ? id : 0)) * 64;
  float acc[64];
  #pragma unroll
  for (int v = 0; v < 64; ++v) acc[v] = 0.f;
  for (int k = 0; k < 64; ++k) {
    float qv = valid ? krow[k] : (float)qrow[k];
    const f32x4* gr = (const f32x4*)&G[k * 64];
    #pragma unroll
    for (int i = 0; i < 16; ++i) {
      f32x4 gv = gr[i];
      acc[i * 4 + 0] += qv * gv[0];
      acc[i * 4 + 1] += qv * gv[1];
      acc[i * 4 + 2] += qv * gv[2];
      acc[i * 4 + 3] += qv * gv[3];
    }
  }
  bf16_t* orow = rb + (((size_t)(b * 2048 + t) * 16) + h) * 64;
  #pragma unroll
  for (int i = 0; i < 8; ++i) {
    bf16x8 ov;
    #pragma unroll
    for (int j = 0; j < 8; ++j) ov[j] = (bf16_t)acc[i * 8 + j];
    *(bf16x8*)(orow + i * 8) = ov;
  }
}

// ---------------------------------------------------------------------------
// out = x + 0.3*local + gate_mean[token]*retr ; 8 elems per thread
__global__ __launch_bounds__(256) void final_kernel(const float* __restrict__ x,
                                                    const bf16_t* __restrict__ lb,
                                                    const bf16_t* __restrict__ rbuf,
                                                    const float* __restrict__ gm,
                                                    float* __restrict__ out) {
  int i = blockIdx.x * 256 + threadIdx.x;     // 524288 groups of 8
  float g = gm[i >> 7];                        // 128 groups per token
  bf16x8 lv = ((const bf16x8*)lb)[i];
  bf16x8 rv = ((const bf16x8*)rbuf)[i];
  const f32x4* xr = (const f32x4*)x;
  f32x4 x0 = xr[i * 2], x1 = xr[i * 2 + 1];
  f32x4 o0, o1;
  #pragma unroll
  for (int j = 0; j < 4; ++j) {
    o0[j] = x0[j] + 0.3f * (float)lv[j]     + g * (float)rv[j];
    o1[j] = x1[j] + 0.3f * (float)lv[j + 4] + g * (float)rv[j + 4];
  }
  f32x4* od = (f32x4*)out;
  od[i * 2] = o0;
  od[i * 2 + 1] = o1;
}

// ---------------------------------------------------------------------------
extern "C" void kernel_launch(void* const* d_in, const int* in_sizes, int n_in,
                              void* d_out, int out_size, void* d_ws, size_t ws_size,
                              hipStream_t stream) {
  const float* x        = (const float*)d_in[0];
  const float* gdn      = (const float*)d_in[1];
  const int*   ids      = (const int*)d_in[2];
  const float* key_bank = (const float*)d_in[3];
  const float* norm_w   = (const float*)d_in[4];
  const float* wq       = (const float*)d_in[5];
  const float* wk       = (const float*)d_in[6];
  const float* wv       = (const float*)d_in[7];
  const float* wo       = (const float*)d_in[8];
  const float* w_gq     = (const float*)d_in[9];
  const float* w_ro     = (const float*)d_in[10];
  const float* w_gate   = (const float*)d_in[11];
  const float* b_gate   = (const float*)d_in[12];

  char* p = (char*)d_ws;
  auto alloc = [&](size_t bytes) { char* r = p; p += (bytes + 255) & ~(size_t)255; return r; };
  const size_t ACT = (size_t)4096 * 1024 * 2;   // bf16 activation (8.4 MB)
  const size_t WTB = (size_t)1024 * 1024 * 2;   // bf16 weight (2.1 MB)
  bf16_t* xn_b   = (bf16_t*)alloc(ACT);
  bf16_t* wq_b   = (bf16_t*)alloc(WTB);
  bf16_t* wk_b   = (bf16_t*)alloc(WTB);
  bf16_t* wv_b   = (bf16_t*)alloc(WTB);
  bf16_t* wo_b   = (bf16_t*)alloc(WTB);
  bf16_t* wgq_b  = (bf16_t*)alloc(WTB);
  bf16_t* wro_b  = (bf16_t*)alloc(WTB);
  bf16_t* qb     = (bf16_t*)alloc(ACT);
  bf16_t* kb     = (bf16_t*)alloc(ACT);
  bf16_t* vb     = (bf16_t*)alloc(ACT);
  bf16_t* qgb    = (bf16_t*)alloc(ACT);
  bf16_t* attn_b = (bf16_t*)alloc(ACT);
  bf16_t* retr_b = (bf16_t*)alloc(ACT);
  bf16_t* local_b= (bf16_t*)alloc(ACT);
  bf16_t* retro_b= (bf16_t*)alloc(ACT);
  float*  gmean  = (float*)alloc(4096 * 4);

  CvtArgs ca;
  ca.s[0] = wq;   ca.d[0] = wq_b;
  ca.s[1] = wk;   ca.d[1] = wk_b;
  ca.s[2] = wv;   ca.d[2] = wv_b;
  ca.s[3] = wo;   ca.d[3] = wo_b;
  ca.s[4] = w_gq; ca.d[4] = wgq_b;
  ca.s[5] = w_ro; ca.d[5] = wro_b;
  convert6<<<dim3(1024, 6), 256, 0, stream>>>(ca);
  rmsnorm_kernel<<<4096, 256, 0, stream>>>(x, norm_w, xn_b);

  GemmCfg g4;
  g4.seg[0] = {xn_b, wq_b,  (void*)qb};
  g4.seg[1] = {xn_b, wk_b,  (void*)kb};
  g4.seg[2] = {xn_b, wv_b,  (void*)vb};
  g4.seg[3] = {xn_b, wgq_b, (void*)qgb};
  g4.bf16out = 1;
  gemm_bt<<<dim3(32, 32), 256, 0, stream>>>(g4);

  rope_kernel<<<8192, 256, 0, stream>>>(qb, kb);
  attn_kernel<<<512, 128, 0, stream>>>(qb, kb, vb, attn_b);
  gate_kernel<<<1024, 256, 0, stream>>>(xn_b, w_gate, b_gate, gmean);
  retrieval_kernel<<<256, 256, 0, stream>>>(qgb, ids, key_bank, gdn, retr_b);

  GemmCfg g2;
  g2.seg[0] = {attn_b, wo_b,  (void*)local_b};
  g2.seg[1] = {retr_b, wro_b, (void*)retro_b};
  g2.seg[2] = g2.seg[0];
  g2.seg[3] = g2.seg[0];
  g2.bf16out = 1;
  gemm_bt<<<dim3(16, 32), 256, 0, stream>>>(g2);

  final_kernel<<<2048, 256, 0, stream>>>(x, local_b, retro_b, gmean, (float*)d_out);
}

// Round 2
// 263.378 us; speedup vs baseline: 1.8946x; 1.8946x over previous
//
#include <hip/hip_runtime.h>
#include <cstddef>

typedef __bf16 bf16_t;
typedef __bf16 bf16x8 __attribute__((ext_vector_type(8)));
typedef __bf16 bf16x4 __attribute__((ext_vector_type(4)));
typedef float  f32x4  __attribute__((ext_vector_type(4)));

// Problem constants: B=2, T=2048, D=1024, H=16, K=V=64, W=256
// ---------------------------------------------------------------------------
// RMSNorm + bf16 cast: one block per token row (4096 rows), 256 thr x 4 elems
__global__ __launch_bounds__(256) void rmsnorm_kernel(const float* __restrict__ x,
                                                      const float* __restrict__ w,
                                                      bf16_t* __restrict__ xn) {
  int t = blockIdx.x;
  int tid = threadIdx.x;
  const f32x4* row = (const f32x4*)(x + (size_t)t * 1024);
  f32x4 v = row[tid];
  float ss = v[0]*v[0] + v[1]*v[1] + v[2]*v[2] + v[3]*v[3];
  #pragma unroll
  for (int off = 32; off >= 1; off >>= 1) ss += __shfl_xor(ss, off);
  __shared__ float red[4];
  int wave = tid >> 6;
  if ((tid & 63) == 0) red[wave] = ss;
  __syncthreads();
  float tot = red[0] + red[1] + red[2] + red[3];
  float rinv = rsqrtf(tot * (1.0f / 1024.0f) + 1e-6f);
  f32x4 wv = ((const f32x4*)w)[tid];
  bf16x4 o;
  #pragma unroll
  for (int i = 0; i < 4; ++i) o[i] = (bf16_t)(v[i] * rinv * wv[i]);
  *(bf16x4*)(xn + (size_t)t * 1024 + tid * 4) = o;
}

// ---------------------------------------------------------------------------
// fp32 -> bf16 weight conversion, 6 matrices of 1024x1024
struct CvtArgs { const float* s[6]; bf16_t* d[6]; };
__global__ __launch_bounds__(256) void convert6(CvtArgs a) {
  const f32x4* src = (const f32x4*)a.s[blockIdx.y];
  bf16_t* dst = a.d[blockIdx.y];
  int i = blockIdx.x * 256 + threadIdx.x;    // 262144 f32x4 per matrix
  f32x4 v = src[i];
  bf16x4 o;
  #pragma unroll
  for (int j = 0; j < 4; ++j) o[j] = (bf16_t)v[j];
  *(bf16x4*)(dst + (size_t)i * 4) = o;
}

// ---------------------------------------------------------------------------
// bf16 MFMA GEMM, C = A (Mx1024) * W^T (1024x1024), W row-major (N x Kd).
struct GemmSeg { const bf16_t* a; const bf16_t* w; void* c; };
struct GemmCfg { GemmSeg seg[4]; int bf16out; };
#define LDSK 40
__global__ __launch_bounds__(256, 2) void gemm_bt(GemmCfg cfg) {
  __shared__ bf16_t As[128 * LDSK];
  __shared__ bf16_t Bs[128 * LDSK];
  int seg = blockIdx.x >> 3;
  const bf16_t* __restrict__ A = cfg.seg[seg].a;
  const bf16_t* __restrict__ W = cfg.seg[seg].w;
  int m0 = blockIdx.y * 128;
  int n0 = (blockIdx.x & 7) * 128;
  int tid = threadIdx.x;
  int lane = tid & 63, wave = tid >> 6;
  int wm = (wave >> 1) * 64, wn = (wave & 1) * 64;
  int l16 = lane & 15, quad = lane >> 4;
  f32x4 acc[4][4] = {};
  for (int k0 = 0; k0 < 1024; k0 += 32) {
    __syncthreads();
    #pragma unroll
    for (int c = 0; c < 2; ++c) {
      int ci = tid + c * 256;          // 0..511 16B-chunks
      int r = ci >> 2;                 // tile row 0..127
      int ko = (ci & 3) * 8;           // k offset 0/8/16/24
      *(uint4*)&As[r * LDSK + ko] = *(const uint4*)&A[(size_t)(m0 + r) * 1024 + k0 + ko];
      *(uint4*)&Bs[r * LDSK + ko] = *(const uint4*)&W[(size_t)(n0 + r) * 1024 + k0 + ko];
    }
    __syncthreads();
    bf16x8 af[4], bfr[4];
    #pragma unroll
    for (int i = 0; i < 4; ++i) {
      af[i]  = *(const bf16x8*)&As[(wm + i * 16 + l16) * LDSK + quad * 8];
      bfr[i] = *(const bf16x8*)&Bs[(wn + i * 16 + l16) * LDSK + quad * 8];
    }
    #pragma unroll
    for (int i = 0; i < 4; ++i)
      #pragma unroll
      for (int j = 0; j < 4; ++j)
        acc[i][j] = __builtin_amdgcn_mfma_f32_16x16x32_bf16(af[i], bfr[j], acc[i][j], 0, 0, 0);
  }
  // C/D layout: col = lane&15, row = quad*4 + reg
  if (cfg.bf16out) {
    bf16_t* C = (bf16_t*)cfg.seg[seg].c;
    #pragma unroll
    for (int i = 0; i < 4; ++i)
      #pragma unroll
      for (int j = 0; j < 4; ++j) {
        int row = m0 + wm + i * 16 + quad * 4;
        int col = n0 + wn + j * 16 + l16;
        #pragma unroll
        for (int r = 0; r < 4; ++r)
          C[(size_t)(row + r) * 1024 + col] = (bf16_t)acc[i][j][r];
      }
  } else {
    float* C = (float*)cfg.seg[seg].c;
    #pragma unroll
    for (int i = 0; i < 4; ++i)
      #pragma unroll
      for (int j = 0; j < 4; ++j) {
        int row = m0 + wm + i * 16 + quad * 4;
        int col = n0 + wn + j * 16 + l16;
        #pragma unroll
        for (int r = 0; r < 4; ++r)
          C[(size_t)(row + r) * 1024 + col] = acc[i][j][r];
      }
  }
}

// ---------------------------------------------------------------------------
// RoPE on q and k (bf16 in/out). One thread per (b,t,h,d<32) pair.
__global__ __launch_bounds__(256) void rope_kernel(bf16_t* __restrict__ q,
                                                   bf16_t* __restrict__ k) {
  int idx = blockIdx.x * 256 + threadIdx.x;   // < 2*2048*16*32 = 2097152
  int d = idx & 31;
  int h = (idx >> 5) & 15;
  int t = (idx >> 9) & 2047;
  int b = idx >> 20;
  float inv = expf((float)d * (-2.0f / 64.0f) * 9.210340371976184f); // 10000^(-2d/64)
  float f = (float)t * inv;
  float sn, cs;
  sincosf(f, &sn, &cs);
  size_t base = (((size_t)(b * 2048 + t) * 16) + h) * 64;
  float q1 = (float)q[base + d], q2 = (float)q[base + d + 32];
  q[base + d]      = (bf16_t)(q1 * cs - q2 * sn);
  q[base + d + 32] = (bf16_t)(q2 * cs + q1 * sn);
  float k1 = (float)k[base + d], k2 = (float)k[base + d + 32];
  k[base + d]      = (bf16_t)(k1 * cs - k2 * sn);
  k[base + d + 32] = (bf16_t)(k2 * cs + k1 * sn);
}

// ---------------------------------------------------------------------------
// MFMA flash attention. Block = 256 thr (4 waves), wave = 16 queries.
// Grid 1024 = 32 tchunks x 16 heads x 2 batch. Window: s in [t-256, t].
// Per 64-key chunk: stage Ks[key][dim], Vt[v][key] (transposed) in LDS.
// S^T = K*Q^T via mfma (keys=A rows, Q=B cols) -> online softmax per
// column-lane -> P regroup via shuffles -> O^T += V^T * P via mfma.
__global__ __launch_bounds__(256) void attn_mfma(const bf16_t* __restrict__ qb,
                                                 const bf16_t* __restrict__ kb,
                                                 const bf16_t* __restrict__ vb,
                                                 bf16_t* __restrict__ ob) {
  __shared__ bf16_t Ks[64 * 72];
  __shared__ bf16_t Vt[64 * 72];
  __shared__ float  Os[4][16 * 68];
  int blk = blockIdx.x;
  int tcb = blk & 31;
  int h = (blk >> 5) & 15;
  int b = blk >> 9;
  int t0 = tcb * 64;
  int tid = threadIdx.x;
  int wv = tid >> 6, lane = tid & 63;
  int l15 = lane & 15, quad = lane >> 4;
  int tq0 = t0 + wv * 16;
  int t = tq0 + l15;
  int lo = t - 256; if (lo < 0) lo = 0;

  // Q fragments (B-operand layout): lane holds Q[l15][quad*8 + j]
  const bf16_t* qptr = qb + (((size_t)(b * 2048 + t) * 16) + h) * 64;
  bf16x8 qf0 = *(const bf16x8*)(qptr + quad * 8);
  bf16x8 qf1 = *(const bf16x8*)(qptr + 32 + quad * 8);

  f32x4 acc[4] = {};           // O^T: acc[vt] col=q(l15), row=v=vt*16+quad*4+r
  float mrun = -1e30f, lrun = 0.f;

  for (int c = 0; c < 5; ++c) {
    int s0 = t0 - 256 + c * 64;
    __syncthreads();
    // ---- stage K: 64 keys x 64 dims, b128 writes
    #pragma unroll
    for (int it = 0; it < 2; ++it) {
      int task = tid + it * 256;
      int key = task >> 3, dseg = task & 7;
      int s = s0 + key; s = s < 0 ? 0 : (s > 2047 ? 2047 : s);
      *(bf16x8*)&Ks[key * 72 + dseg * 8] =
        *(const bf16x8*)(kb + (((size_t)(b * 2048 + s) * 16) + h) * 64 + dseg * 8);
    }
    // ---- stage V transposed: Vt[v][key], paired-key b32 writes
    {
      int vseg = tid & 7, kp = tid >> 3;      // kp 0..31
      int sA = s0 + 2 * kp, sB = sA + 1;
      sA = sA < 0 ? 0 : (sA > 2047 ? 2047 : sA);
      sB = sB < 0 ? 0 : (sB > 2047 ? 2047 : sB);
      bf16x8 va = *(const bf16x8*)(vb + (((size_t)(b * 2048 + sA) * 16) + h) * 64 + vseg * 8);
      bf16x8 vbv = *(const bf16x8*)(vb + (((size_t)(b * 2048 + sB) * 16) + h) * 64 + vseg * 8);
      #pragma unroll
      for (int j = 0; j < 8; ++j) {
        union { bf16_t h2[2]; unsigned int u; } pk;
        pk.h2[0] = va[j]; pk.h2[1] = vbv[j];
        *(unsigned int*)&Vt[(vseg * 8 + j) * 72 + 2 * kp] = pk.u;
      }
    }
    __syncthreads();
    // ---- compute: two 32-key pairs per chunk
    #pragma unroll
    for (int p = 0; p < 2; ++p) {
      int sbase = s0 + p * 32;
      // wave-uniform skip of fully-masked pairs
      if (sbase > tq0 + 15 || sbase + 31 < tq0 - 256 || sbase + 31 < 0) continue;
      int kl = p * 32;
      bf16x8 ka0  = *(const bf16x8*)&Ks[(kl + l15) * 72 + quad * 8];
      bf16x8 ka0b = *(const bf16x8*)&Ks[(kl + l15) * 72 + 32 + quad * 8];
      bf16x8 ka1  = *(const bf16x8*)&Ks[(kl + 16 + l15) * 72 + quad * 8];
      bf16x8 ka1b = *(const bf16x8*)&Ks[(kl + 16 + l15) * 72 + 32 + quad * 8];
      f32x4 c0 = {}, c1 = {};
      c0 = __builtin_amdgcn_mfma_f32_16x16x32_bf16(ka0,  qf0, c0, 0, 0, 0);
      c0 = __builtin_amdgcn_mfma_f32_16x16x32_bf16(ka0b, qf1, c0, 0, 0, 0);
      c1 = __builtin_amdgcn_mfma_f32_16x16x32_bf16(ka1,  qf0, c1, 0, 0, 0);
      c1 = __builtin_amdgcn_mfma_f32_16x16x32_bf16(ka1b, qf1, c1, 0, 0, 0);
      // mask + scale; scores for col q = l15, row keys sbase + {quad*4+r, 16+...}
      float p0[4], p1[4];
      float mx = -1e30f;
      #pragma unroll
      for (int r = 0; r < 4; ++r) {
        int sK0 = sbase + quad * 4 + r;
        int sK1 = sK0 + 16;
        float v0 = (sK0 >= lo && sK0 <= t) ? c0[r] * 0.125f : -1e30f;
        float v1 = (sK1 >= lo && sK1 <= t) ? c1[r] * 0.125f : -1e30f;
        p0[r] = v0; p1[r] = v1;
        mx = fmaxf(mx, fmaxf(v0, v1));
      }
      mx = fmaxf(mx, __shfl_xor(mx, 16));
      mx = fmaxf(mx, __shfl_xor(mx, 32));
      float mnew = fmaxf(mrun, mx);
      float alpha = __expf(mrun - mnew);
      float rs = 0.f;
      #pragma unroll
      for (int r = 0; r < 4; ++r) {
        float e0 = (p0[r] > -1e29f) ? __expf(p0[r] - mnew) : 0.f;
        float e1 = (p1[r] > -1e29f) ? __expf(p1[r] - mnew) : 0.f;
        p0[r] = e0; p1[r] = e1;
        rs += e0 + e1;
      }
      rs += __shfl_xor(rs, 16);
      rs += __shfl_xor(rs, 32);
      mrun = mnew;
      lrun = lrun * alpha + rs;
      #pragma unroll
      for (int vt = 0; vt < 4; ++vt)
        #pragma unroll
        for (int r = 0; r < 4; ++r) acc[vt][r] *= alpha;
      // pack P (4 keys/lane) and regroup to B-frag (8 keys/lane)
      union { bf16x4 v; int2 i2; } pka, pkb;
      #pragma unroll
      for (int r = 0; r < 4; ++r) { pka.v[r] = (bf16_t)p0[r]; pkb.v[r] = (bf16_t)p1[r]; }
      int sel = quad >> 1;
      int base = l15 + ((quad & 1) << 5);
      int a0 = __shfl(pka.i2.x, base),      b0 = __shfl(pkb.i2.x, base);
      int a1 = __shfl(pka.i2.y, base),      b1 = __shfl(pkb.i2.y, base);
      int a2 = __shfl(pka.i2.x, base + 16), b2 = __shfl(pkb.i2.x, base + 16);
      int a3 = __shfl(pka.i2.y, base + 16), b3 = __shfl(pkb.i2.y, base + 16);
      union { int4 i4; bf16x8 v; } pf;
      pf.i4.x = sel ? b0 : a0;
      pf.i4.y = sel ? b1 : a1;
      pf.i4.z = sel ? b2 : a2;
      pf.i4.w = sel ? b3 : a3;
      // PV: O^T[v][q] += V^T[v][key] * P^T[key][q]
      #pragma unroll
      for (int vt = 0; vt < 4; ++vt) {
        bf16x8 vfr = *(const bf16x8*)&Vt[(vt * 16 + l15) * 72 + kl + quad * 8];
        acc[vt] = __builtin_amdgcn_mfma_f32_16x16x32_bf16(vfr, pf.v, acc[vt], 0, 0, 0);
      }
    }
  }
  // epilogue: O^T -> LDS transpose -> coalesced bf16 stores
  float rl = 1.0f / lrun;
  float* myOs = &Os[wv][0];
  #pragma unroll
  for (int vt = 0; vt < 4; ++vt)
    #pragma unroll
    for (int r = 0; r < 4; ++r)
      myOs[l15 * 68 + vt * 16 + quad * 4 + r] = acc[vt][r] * rl;
  __syncthreads();
  #pragma unroll
  for (int q = 0; q < 16; ++q) {
    float v = myOs[q * 68 + lane];
    ob[(((size_t)(b * 2048 + tq0 + q) * 16) + h) * 64 + lane] = (bf16_t)v;
  }
}

// ---------------------------------------------------------------------------
// Gate: gm[t] = mean_h sigmoid(xn[t] . w_gate[h] + b_gate[h]); one wave/token
__global__ __launch_bounds__(256, 4) void gate_kernel(const bf16_t* __restrict__ xn,
                                                      const float* __restrict__ wg,
                                                      const float* __restrict__ bg,
                                                      float* __restrict__ gm) {
  int wave = threadIdx.x >> 6, lane = threadIdx.x & 63;
  int t = blockIdx.x * 4 + wave;           // 4096 tokens
  float acc[16];
  #pragma unroll
  for (int h = 0; h < 16; ++h) acc[h] = 0.f;
  const bf16_t* xr = xn + (size_t)t * 1024;
  for (int i = 0; i < 16; ++i) {
    float xv = (float)xr[i * 64 + lane];
    #pragma unroll
    for (int h = 0; h < 16; ++h) acc[h] += xv * wg[h * 1024 + i * 64 + lane];
  }
  #pragma unroll
  for (int h = 0; h < 16; ++h) {
    float s = acc[h];
    #pragma unroll
    for (int off = 32; off >= 1; off >>= 1) s += __shfl_xor(s, off);
    acc[h] = s;
  }
  if (lane == 0) {
    float g = 0.f;
    #pragma unroll
    for (int h = 0; h < 16; ++h) g += 1.0f / (1.0f + __expf(-(acc[h] + bg[h])));
    gm[t] = g * (1.0f / 16.0f);
  }
}

// ---------------------------------------------------------------------------
// Retrieval: q_g override by key_bank gather, then retrieved = q_g @ gdn[b,h]
__global__ __launch_bounds__(256, 2) void retrieval_kernel(const bf16_t* __restrict__ qgb,
                                                           const int* __restrict__ ids,
                                                           const float* __restrict__ bank,
                                                           const float* __restrict__ gdn,
                                                           bf16_t* __restrict__ rb) {
  __shared__ float G[64 * 64];     // gdn_state[b][h], (k,v) row-major
  int blk = blockIdx.x;            // 256 = 2*16*8
  int tc = blk & 7;
  int h = (blk >> 3) & 15;
  int b = blk >> 7;
  int tid = threadIdx.x;
  const f32x4* gsrc = (const f32x4*)(gdn + (size_t)(b * 16 + h) * 4096);
  #pragma unroll
  for (int it = 0; it < 4; ++it)
    ((f32x4*)G)[tid + it * 256] = gsrc[tid + it * 256];
  __syncthreads();
  int t = tc * 256 + tid;
  int id = ids[b * 2048 + t] - 50250;
  bool valid = (id >= 0) && (id < 64);
  const bf16_t* qrow = qgb + (((size_t)(b * 2048 + t) * 16) + h) * 64;
  const float* krow = bank + (size_t)(h * 64 + (valid ? id : 0)) * 64;
  float acc[64];
  #pragma unroll
  for (int v = 0; v < 64; ++v) acc[v] = 0.f;
  for (int k = 0; k < 64; ++k) {
    float qv = valid ? krow[k] : (float)qrow[k];
    const f32x4* gr = (const f32x4*)&G[k * 64];
    #pragma unroll
    for (int i = 0; i < 16; ++i) {
      f32x4 gv = gr[i];
      acc[i * 4 + 0] += qv * gv[0];
      acc[i * 4 + 1] += qv * gv[1];
      acc[i * 4 + 2] += qv * gv[2];
      acc[i * 4 + 3] += qv * gv[3];
    }
  }
  bf16_t* orow = rb + (((size_t)(b * 2048 + t) * 16) + h) * 64;
  #pragma unroll
  for (int i = 0; i < 8; ++i) {
    bf16x8 ov;
    #pragma unroll
    for (int j = 0; j < 8; ++j) ov[j] = (bf16_t)acc[i * 8 + j];
    *(bf16x8*)(orow + i * 8) = ov;
  }
}

// ---------------------------------------------------------------------------
// out = x + 0.3*local + gate_mean[token]*retr ; 8 elems per thread
__global__ __launch_bounds__(256) void final_kernel(const float* __restrict__ x,
                                                    const bf16_t* __restrict__ lb,
                                                    const bf16_t* __restrict__ rbuf,
                                                    const float* __restrict__ gm,
                                                    float* __restrict__ out) {
  int i = blockIdx.x * 256 + threadIdx.x;     // 524288 groups of 8
  float g = gm[i >> 7];                        // 128 groups per token
  bf16x8 lv = ((const bf16x8*)lb)[i];
  bf16x8 rv = ((const bf16x8*)rbuf)[i];
  const f32x4* xr = (const f32x4*)x;
  f32x4 x0 = xr[i * 2], x1 = xr[i * 2 + 1];
  f32x4 o0, o1;
  #pragma unroll
  for (int j = 0; j < 4; ++j) {
    o0[j] = x0[j] + 0.3f * (float)lv[j]     + g * (float)rv[j];
    o1[j] = x1[j] + 0.3f * (float)lv[j + 4] + g * (float)rv[j + 4];
  }
  f32x4* od = (f32x4*)out;
  od[i * 2] = o0;
  od[i * 2 + 1] = o1;
}

// ---------------------------------------------------------------------------
extern "C" void kernel_launch(void* const* d_in, const int* in_sizes, int n_in,
                              void* d_out, int out_size, void* d_ws, size_t ws_size,
                              hipStream_t stream) {
  const float* x        = (const float*)d_in[0];
  const float* gdn      = (const float*)d_in[1];
  const int*   ids      = (const int*)d_in[2];
  const float* key_bank = (const float*)d_in[3];
  const float* norm_w   = (const float*)d_in[4];
  const float* wq       = (const float*)d_in[5];
  const float* wk       = (const float*)d_in[6];
  const float* wv       = (const float*)d_in[7];
  const float* wo       = (const float*)d_in[8];
  const float* w_gq     = (const float*)d_in[9];
  const float* w_ro     = (const float*)d_in[10];
  const float* w_gate   = (const float*)d_in[11];
  const float* b_gate   = (const float*)d_in[12];

  char* p = (char*)d_ws;
  auto alloc = [&](size_t bytes) { char* r = p; p += (bytes + 255) & ~(size_t)255; return r; };
  const size_t ACT = (size_t)4096 * 1024 * 2;   // bf16 activation (8.4 MB)
  const size_t WTB = (size_t)1024 * 1024 * 2;   // bf16 weight (2.1 MB)
  bf16_t* xn_b   = (bf16_t*)alloc(ACT);
  bf16_t* wq_b   = (bf16_t*)alloc(WTB);
  bf16_t* wk_b   = (bf16_t*)alloc(WTB);
  bf16_t* wv_b   = (bf16_t*)alloc(WTB);
  bf16_t* wo_b   = (bf16_t*)alloc(WTB);
  bf16_t* wgq_b  = (bf16_t*)alloc(WTB);
  bf16_t* wro_b  = (bf16_t*)alloc(WTB);
  bf16_t* qb     = (bf16_t*)alloc(ACT);
  bf16_t* kb     = (bf16_t*)alloc(ACT);
  bf16_t* vb     = (bf16_t*)alloc(ACT);
  bf16_t* qgb    = (bf16_t*)alloc(ACT);
  bf16_t* attn_b = (bf16_t*)alloc(ACT);
  bf16_t* retr_b = (bf16_t*)alloc(ACT);
  bf16_t* local_b= (bf16_t*)alloc(ACT);
  bf16_t* retro_b= (bf16_t*)alloc(ACT);
  float*  gmean  = (float*)alloc(4096 * 4);

  CvtArgs ca;
  ca.s[0] = wq;   ca.d[0] = wq_b;
  ca.s[1] = wk;   ca.d[1] = wk_b;
  ca.s[2] = wv;   ca.d[2] = wv_b;
  ca.s[3] = wo;   ca.d[3] = wo_b;
  ca.s[4] = w_gq; ca.d[4] = wgq_b;
  ca.s[5] = w_ro; ca.d[5] = wro_b;
  convert6<<<dim3(1024, 6), 256, 0, stream>>>(ca);
  rmsnorm_kernel<<<4096, 256, 0, stream>>>(x, norm_w, xn_b);

  GemmCfg g4;
  g4.seg[0] = {xn_b, wq_b,  (void*)qb};
  g4.seg[1] = {xn_b, wk_b,  (void*)kb};
  g4.seg[2] = {xn_b, wv_b,  (void*)vb};
  g4.seg[3] = {xn_b, wgq_b, (void*)qgb};
  g4.bf16out = 1;
  gemm_bt<<<dim3(32, 32), 256, 0, stream>>>(g4);

  rope_kernel<<<8192, 256, 0, stream>>>(qb, kb);
  attn_mfma<<<1024, 256, 0, stream>>>(qb, kb, vb, attn_b);
  gate_kernel<<<1024, 256, 0, stream>>>(xn_b, w_gate, b_gate, gmean);
  retrieval_kernel<<<256, 256, 0, stream>>>(qgb, ids, key_bank, gdn, retr_b);

  GemmCfg g2;
  g2.seg[0] = {attn_b, wo_b,  (void*)local_b};
  g2.seg[1] = {retr_b, wro_b, (void*)retro_b};
  g2.seg[2] = g2.seg[0];
  g2.seg[3] = g2.seg[0];
  g2.bf16out = 1;
  gemm_bt<<<dim3(16, 32), 256, 0, stream>>>(g2);

  final_kernel<<<2048, 256, 0, stream>>>(x, local_b, retro_b, gmean, (float*)d_out);
}